// Round 1
// baseline (20124.382 us; speedup 1.0000x reference)
//
#include <hip/hip_runtime.h>
#include <stdint.h>

#define BETA 0.9f

typedef unsigned short u16;

// ---------------------------------------------------------------------------
// prep: transpose weights into ws layouts used by the layer kernels
//   W2T [256][3][128]  from W2 [128][256][3]
//   W3T [128][3][64]   from W3 [64][128][3]
//   fw1T [256][100]    from fw1 [100][256]
//   fw2T [100][40]     from fw2 [40][100]
// ---------------------------------------------------------------------------
__global__ void prep_kernel(const float* __restrict__ W2, const float* __restrict__ W3,
                            const float* __restrict__ fw1, const float* __restrict__ fw2,
                            float* __restrict__ W2T, float* __restrict__ W3T,
                            float* __restrict__ fw1T, float* __restrict__ fw2T) {
  int o = blockIdx.x * 256 + threadIdx.x;
  if (o < 98304) {
    int ci = o / 384, r = o % 384, k = r / 128, co = r % 128;
    W2T[o] = W2[(co * 256 + ci) * 3 + k];
  }
  int o2 = o - 98304;
  if (o2 >= 0 && o2 < 24576) {
    int ci = o2 / 192, r = o2 % 192, k = r / 64, co = r % 64;
    W3T[o2] = W3[(co * 128 + ci) * 3 + k];
  }
  int o3 = o - (98304 + 24576);
  if (o3 >= 0 && o3 < 25600) {
    int f = o3 / 100, i = o3 % 100;
    fw1T[o3] = fw1[i * 256 + f];
  }
  int o4 = o - (98304 + 24576 + 25600);
  if (o4 >= 0 && o4 < 4000) {
    int i = o4 / 40, j = o4 % 40;
    fw2T[o4] = fw2[i * 100 + j];
  }
}

// ---------------------------------------------------------------------------
// conv1 (2->256, K=5, pad=2) + LIF1 over 16 steps, cur1 constant across t.
// Output: bit-packed spikes s1bits[b][co][l] (bit t = spike at step t).
// Block: (b, co-tile of 8). Thread: one co x 4 l-positions.
// ---------------------------------------------------------------------------
__global__ __launch_bounds__(256) void conv1_lif_kernel(
    const float* __restrict__ x, const float* __restrict__ W1,
    const float* __restrict__ b1, u16* __restrict__ s1bits) {
  __shared__ float xl[2][132];  // l in [-2, 129]
  int b = blockIdx.x;
  int tid = threadIdx.x;
  for (int i = tid; i < 264; i += 256) {
    int ci = i / 132, idx = i % 132, lg = idx - 2;
    xl[ci][idx] = (lg >= 0 && lg < 128) ? x[(b * 2 + ci) * 128 + lg] : 0.0f;
  }
  __syncthreads();
  int co = blockIdx.y * 8 + (tid >> 5);
  int tx = tid & 31;  // l-group: l = 4*tx + j
  float w[2][5];
#pragma unroll
  for (int ci = 0; ci < 2; ++ci)
#pragma unroll
    for (int k = 0; k < 5; ++k) w[ci][k] = W1[(co * 2 + ci) * 5 + k];
  float bias = b1[co];
  float cur[4];
#pragma unroll
  for (int j = 0; j < 4; ++j) {
    float acc = bias;
#pragma unroll
    for (int ci = 0; ci < 2; ++ci)
#pragma unroll
      for (int k = 0; k < 5; ++k) acc += w[ci][k] * xl[ci][4 * tx + j + k];
    cur[j] = acc;
  }
  float m[4] = {0.f, 0.f, 0.f, 0.f}, sp[4] = {0.f, 0.f, 0.f, 0.f};
  uint32_t bits[4] = {0u, 0u, 0u, 0u};
#pragma unroll
  for (int t = 0; t < 16; ++t) {
#pragma unroll
    for (int j = 0; j < 4; ++j) {
      m[j] = BETA * m[j] + cur[j] - sp[j];
      bool s = m[j] > 1.0f;
      bits[j] |= ((uint32_t)s) << t;
      sp[j] = s ? 1.0f : 0.0f;
    }
  }
  uint2 v;
  v.x = (bits[0] & 0xFFFFu) | (bits[1] << 16);
  v.y = (bits[2] & 0xFFFFu) | (bits[3] << 16);
  *(uint2*)&s1bits[(b * 256 + co) * 128 + 4 * tx] = v;
}

// ---------------------------------------------------------------------------
// Generic conv (CIN -> COUT, K=3, pad=1) on bit-packed spikes + LIF.
// Block tile: 32 co x 32 l, all 16 t. Thread: 2co x 2l x 16t accumulators.
// K-loop chunked by 16 ci; spikes unpacked to fp32 LDS (stride 18 pad),
// weights staged to LDS per chunk.
// ---------------------------------------------------------------------------
template <int CIN>
__global__ __launch_bounds__(256, 2) void conv_lif_kernel(
    const u16* __restrict__ sin_bits, const float* __restrict__ WT,
    const float* __restrict__ bias, u16* __restrict__ sout_bits, int COUT) {
  __shared__ float sf[16][34][18];  // [ci][row=l_local+1 from -1][t], pad 18
  __shared__ float Wl[1536];        // [ci16][k3][co32]
  int b = blockIdx.x, cb = blockIdx.y * 32, lb = blockIdx.z * 32;
  int tid = threadIdx.x, lx = tid & 15, ty = tid >> 4;

  float acc[2][2][16];
#pragma unroll
  for (int c = 0; c < 2; ++c)
#pragma unroll
    for (int d = 0; d < 2; ++d)
#pragma unroll
      for (int t = 0; t < 16; ++t) acc[c][d][t] = 0.0f;

  const int NCHUNK = CIN / 16;
  for (int chunk = 0; chunk < NCHUNK; ++chunk) {
    int c0 = chunk * 16;
    // stage weights: 1536 floats, layout identity [ci][k][co]
#pragma unroll
    for (int j = 0; j < 6; ++j) {
      int i = tid + j * 256;
      int ci = i / 96, r = i % 96, k = r >> 5, co = r & 31;
      Wl[i] = WT[(c0 + ci) * 3 * COUT + k * COUT + cb + co];
    }
    // stage spike floats: 16 ci x 34 rows (l in [lb-1, lb+32])
    for (int mi = tid; mi < 544; mi += 256) {
      int ci = mi / 34, row = mi % 34;
      int lg = lb + row - 1;
      uint32_t v = 0;
      if (lg >= 0 && lg < 128) v = sin_bits[(b * CIN + c0 + ci) * 128 + lg];
#pragma unroll
      for (int t = 0; t < 16; ++t) sf[ci][row][t] = (float)((v >> t) & 1u);
    }
    __syncthreads();

    for (int ci = 0; ci < 16; ++ci) {
      const float* frow = &sf[ci][2 * lx][0];
      float f[4][16];
#pragma unroll
      for (int r = 0; r < 4; ++r)
#pragma unroll
        for (int t = 0; t < 16; ++t) f[r][t] = frow[r * 18 + t];
      float2 w[3];
#pragma unroll
      for (int k = 0; k < 3; ++k)
        w[k] = *(const float2*)&Wl[(ci * 3 + k) * 32 + 2 * ty];
#pragma unroll
      for (int k = 0; k < 3; ++k) {
#pragma unroll
        for (int t = 0; t < 16; ++t) {
          acc[0][0][t] = fmaf(w[k].x, f[k][t], acc[0][0][t]);
          acc[0][1][t] = fmaf(w[k].x, f[k + 1][t], acc[0][1][t]);
          acc[1][0][t] = fmaf(w[k].y, f[k][t], acc[1][0][t]);
          acc[1][1][t] = fmaf(w[k].y, f[k + 1][t], acc[1][1][t]);
        }
      }
    }
    __syncthreads();
  }

  // LIF + pack + store
#pragma unroll
  for (int c = 0; c < 2; ++c) {
    int co = cb + 2 * ty + c;
    float bc = bias[co];
    uint32_t ob[2];
#pragma unroll
    for (int d = 0; d < 2; ++d) {
      float m = 0.f, sp = 0.f;
      uint32_t bits = 0;
#pragma unroll
      for (int t = 0; t < 16; ++t) {
        m = BETA * m + (acc[c][d][t] + bc) - sp;
        bool s = m > 1.0f;
        bits |= ((uint32_t)s) << t;
        sp = s ? 1.0f : 0.0f;
      }
      ob[d] = bits;
    }
    uint32_t packed = (ob[0] & 0xFFFFu) | (ob[1] << 16);
    *(uint32_t*)&sout_bits[(b * COUT + co) * 128 + lb + 2 * lx] = packed;
  }
}

// ---------------------------------------------------------------------------
// head: conv4 (64->2, K=3) + LIF4, flatten, fc1 (256->100) + LIF5,
// fc2 (100->40) accumulated over t (popcount trick), /16 + fb2.
// One block per batch element.
// ---------------------------------------------------------------------------
__global__ __launch_bounds__(256) void head_kernel(
    const u16* __restrict__ s3bits, const float* __restrict__ W4,
    const float* __restrict__ b4, const float* __restrict__ fw1T,
    const float* __restrict__ fb1, const float* __restrict__ fw2T,
    const float* __restrict__ fb2, float* __restrict__ out) {
  __shared__ u16 s3l[64][130];  // l in [-1, 128]
  __shared__ float W4l[384];
  __shared__ u16 flat4[256];
  __shared__ u16 s5b[100];
  int b = blockIdx.x, tid = threadIdx.x;

  for (int i = tid; i < 64 * 130; i += 256) {
    int ci = i / 130, idx = i % 130, lg = idx - 1;
    s3l[ci][idx] = (lg >= 0 && lg < 128) ? s3bits[(b * 64 + ci) * 128 + lg] : (u16)0;
  }
  for (int i = tid; i < 384; i += 256) W4l[i] = W4[i];
  __syncthreads();

  // conv4 + LIF4: thread = flat position co*128 + l
  {
    int co = tid >> 7, l = tid & 127;
    float acc4[16];
#pragma unroll
    for (int t = 0; t < 16; ++t) acc4[t] = 0.f;
    for (int ci = 0; ci < 64; ++ci) {
#pragma unroll
      for (int k = 0; k < 3; ++k) {
        float wv = W4l[(co * 64 + ci) * 3 + k];
        uint32_t msk = s3l[ci][l + k];
#pragma unroll
        for (int t = 0; t < 16; ++t)
          acc4[t] = fmaf(wv, (float)((msk >> t) & 1u), acc4[t]);
      }
    }
    float bc = b4[co];
    float m = 0.f, sp = 0.f;
    uint32_t bits = 0;
#pragma unroll
    for (int t = 0; t < 16; ++t) {
      m = BETA * m + (acc4[t] + bc) - sp;
      bool s = m > 1.0f;
      bits |= ((uint32_t)s) << t;
      sp = s ? 1.0f : 0.0f;
    }
    flat4[tid] = (u16)bits;
  }
  __syncthreads();

  // fc1 + LIF5
  if (tid < 100) {
    float acc5[16];
#pragma unroll
    for (int t = 0; t < 16; ++t) acc5[t] = 0.f;
    for (int f = 0; f < 256; ++f) {
      float wv = fw1T[f * 100 + tid];
      uint32_t msk = flat4[f];
#pragma unroll
      for (int t = 0; t < 16; ++t)
        acc5[t] = fmaf(wv, (float)((msk >> t) & 1u), acc5[t]);
    }
    float bc = fb1[tid];
    float m = 0.f, sp = 0.f;
    uint32_t bits = 0;
#pragma unroll
    for (int t = 0; t < 16; ++t) {
      m = BETA * m + (acc5[t] + bc) - sp;
      bool s = m > 1.0f;
      bits |= ((uint32_t)s) << t;
      sp = s ? 1.0f : 0.0f;
    }
    s5b[tid] = (u16)bits;
  }
  __syncthreads();

  // fc2 accumulated over t: sum_t s5[t][i]*w = w * popcount(bits_i)
  if (tid < 40) {
    float a = 0.f;
    for (int i = 0; i < 100; ++i) {
      float wv = fw2T[i * 40 + tid];
      a = fmaf(wv, (float)__popc((uint32_t)s5b[i]), a);
    }
    out[b * 40 + tid] = a * 0.0625f + fb2[tid];
  }
}

// ---------------------------------------------------------------------------
extern "C" void kernel_launch(void* const* d_in, const int* in_sizes, int n_in,
                              void* d_out, int out_size, void* d_ws, size_t ws_size,
                              hipStream_t stream) {
  const float* x   = (const float*)d_in[0];
  const float* W1  = (const float*)d_in[1];
  const float* b1  = (const float*)d_in[2];
  const float* W2  = (const float*)d_in[3];
  const float* b2  = (const float*)d_in[4];
  const float* W3  = (const float*)d_in[5];
  const float* b3  = (const float*)d_in[6];
  const float* W4  = (const float*)d_in[7];
  const float* b4  = (const float*)d_in[8];
  const float* fw1 = (const float*)d_in[9];
  const float* fb1 = (const float*)d_in[10];
  const float* fw2 = (const float*)d_in[11];
  const float* fb2 = (const float*)d_in[12];
  float* out = (float*)d_out;

  char* ws = (char*)d_ws;
  float* W2T  = (float*)(ws);                        // 393216 B
  float* W3T  = (float*)(ws + 393216);               //  98304 B
  float* fw1T = (float*)(ws + 491520);               // 102400 B
  float* fw2T = (float*)(ws + 593920);               //  16384 B (16000 used)
  u16* s1b = (u16*)(ws + 610304);                    // 134217728 B
  u16* s2b = (u16*)(ws + 610304 + 134217728);        //  67108864 B
  u16* s3b = (u16*)(ws + 610304 + 134217728 + 67108864);  // 33554432 B
  // total: 235,491,328 B

  prep_kernel<<<dim3(596), dim3(256), 0, stream>>>(W2, W3, fw1, fw2, W2T, W3T, fw1T, fw2T);
  conv1_lif_kernel<<<dim3(2048, 32), dim3(256), 0, stream>>>(x, W1, b1, s1b);
  conv_lif_kernel<256><<<dim3(2048, 4, 4), dim3(256), 0, stream>>>(s1b, W2T, b2, s2b, 128);
  conv_lif_kernel<128><<<dim3(2048, 2, 4), dim3(256), 0, stream>>>(s2b, W3T, b3, s3b, 64);
  head_kernel<<<dim3(2048), dim3(256), 0, stream>>>(s3b, W4, b4, fw1T, fb1, fw2T, fb2, out);
}

// Round 2
// 3245.521 us; speedup vs baseline: 6.2007x; 6.2007x over previous
//
#include <hip/hip_runtime.h>
#include <stdint.h>

#define BETA 0.9f

typedef unsigned short u16;
typedef short bf16x8 __attribute__((ext_vector_type(8)));
typedef float f32x4 __attribute__((ext_vector_type(4)));

// ---------------------------------------------------------------------------
// bf16 helpers (manual RN-even conversion; exact 3-way split of fp32)
// ---------------------------------------------------------------------------
__device__ inline u16 to_bf16(float f) {
  union { float f; uint32_t u; } v; v.f = f;
  uint32_t x = v.u;
  return (u16)((x + 0x7FFFu + ((x >> 16) & 1u)) >> 16);
}
__device__ inline float from_bf16(u16 h) {
  union { uint32_t u; float f; } v; v.u = ((uint32_t)h) << 16;
  return v.f;
}
__device__ inline void split3(float w, u16& h, u16& m, u16& l) {
  h = to_bf16(w);
  float r1 = w - from_bf16(h);
  m = to_bf16(r1);
  float r2 = r1 - from_bf16(m);
  l = to_bf16(r2);   // exact: r2 has <= 8 significant bits
}

// ---------------------------------------------------------------------------
// prep: split W2/W3 into 3x bf16 parts, layout [part][tap][co][ci];
// transpose fc weights. (fw2T fixed: true [100][40] transpose, in-bounds.)
// ---------------------------------------------------------------------------
__global__ void prep_kernel(const float* __restrict__ W2, const float* __restrict__ W3,
                            const float* __restrict__ fw1, const float* __restrict__ fw2,
                            u16* __restrict__ A2, u16* __restrict__ A3,
                            float* __restrict__ fw1T, float* __restrict__ fw2T) {
  int o = blockIdx.x * 256 + threadIdx.x;
  // A2: 3 taps x 128 co x 256 ci = 98304 items, part stride 98304
  if (o < 98304) {
    int tap = o >> 15, r = o & 32767, co = r >> 8, ci = r & 255;
    float w = W2[(co * 256 + ci) * 3 + tap];
    u16 h, m, l; split3(w, h, m, l);
    int base = (tap * 128 + co) * 256 + ci;
    A2[base] = h; A2[98304 + base] = m; A2[2 * 98304 + base] = l;
  }
  int o2 = o - 98304;  // A3: 3 x 64 x 128 = 24576 items, part stride 24576
  if (o2 >= 0 && o2 < 24576) {
    int tap = o2 >> 13, r = o2 & 8191, co = r >> 7, ci = r & 127;
    float w = W3[(co * 128 + ci) * 3 + tap];
    u16 h, m, l; split3(w, h, m, l);
    int base = (tap * 64 + co) * 128 + ci;
    A3[base] = h; A3[24576 + base] = m; A3[2 * 24576 + base] = l;
  }
  int o3 = o - (98304 + 24576);
  if (o3 >= 0 && o3 < 25600) {
    int f = o3 / 100, i = o3 % 100;
    fw1T[o3] = fw1[i * 256 + f];           // fw1T[f][i] = fw1[i][f]
  }
  int o4 = o - (98304 + 24576 + 25600);
  if (o4 >= 0 && o4 < 4000) {
    int i = o4 / 40, j = o4 % 40;
    fw2T[o4] = fw2[j * 100 + i];           // fw2T[i][j] = fw2[j][i]
  }
}

// ---------------------------------------------------------------------------
// conv1 (2->256, K=5, pad=2) + LIF1; cur constant across t. (unchanged)
// ---------------------------------------------------------------------------
__global__ __launch_bounds__(256) void conv1_lif_kernel(
    const float* __restrict__ x, const float* __restrict__ W1,
    const float* __restrict__ b1, u16* __restrict__ s1bits) {
  __shared__ float xl[2][132];
  int b = blockIdx.x;
  int tid = threadIdx.x;
  for (int i = tid; i < 264; i += 256) {
    int ci = i / 132, idx = i % 132, lg = idx - 2;
    xl[ci][idx] = (lg >= 0 && lg < 128) ? x[(b * 2 + ci) * 128 + lg] : 0.0f;
  }
  __syncthreads();
  int co = blockIdx.y * 8 + (tid >> 5);
  int tx = tid & 31;
  float w[2][5];
#pragma unroll
  for (int ci = 0; ci < 2; ++ci)
#pragma unroll
    for (int k = 0; k < 5; ++k) w[ci][k] = W1[(co * 2 + ci) * 5 + k];
  float bias = b1[co];
  float cur[4];
#pragma unroll
  for (int j = 0; j < 4; ++j) {
    float acc = bias;
#pragma unroll
    for (int ci = 0; ci < 2; ++ci)
#pragma unroll
      for (int k = 0; k < 5; ++k) acc += w[ci][k] * xl[ci][4 * tx + j + k];
    cur[j] = acc;
  }
  float m[4] = {0.f, 0.f, 0.f, 0.f}, sp[4] = {0.f, 0.f, 0.f, 0.f};
  uint32_t bits[4] = {0u, 0u, 0u, 0u};
#pragma unroll
  for (int t = 0; t < 16; ++t) {
#pragma unroll
    for (int j = 0; j < 4; ++j) {
      m[j] = BETA * m[j] + cur[j] - sp[j];
      bool s = m[j] > 1.0f;
      bits[j] |= ((uint32_t)s) << t;
      sp[j] = s ? 1.0f : 0.0f;
    }
  }
  uint2 v;
  v.x = (bits[0] & 0xFFFFu) | (bits[1] << 16);
  v.y = (bits[2] & 0xFFFFu) | (bits[3] << 16);
  *(uint2*)&s1bits[(b * 256 + co) * 128 + 4 * tx] = v;
}

// ---------------------------------------------------------------------------
// MFMA conv (CIN->COUT, K=3, pad=1) + LIF on bit-packed spikes.
// Block: one b x all COUT x 8 l x 16 t. Waves: 2x2 (wy: m-half, wx: n-half).
// A = weights (3-way bf16 split, exact), B = spikes unpacked to bf16 LDS.
// K chunked by 32 ci; per chunk: B staged once, A staged per split part.
// MFMA 16x16x32_bf16: A[m=lane&15][k=q*8+j], B[k=q*8+j][n=lane&15],
// D[m=q*4+r][n=lane&15]  (k-permutation cancels between A and B).
// ---------------------------------------------------------------------------
template <int CIN, int COUT>
__global__ __launch_bounds__(256) void conv_mfma_kernel(
    const u16* __restrict__ sbits_in, const u16* __restrict__ Ag,
    const float* __restrict__ bias, u16* __restrict__ sbits_out) {
  constexpr int WM = COUT / 2;        // wave M extent
  constexpr int MT = COUT / 32;       // m-tiles per wave
  constexpr int NCHUNK = CIN / 32;
  constexpr int ABYTES = 3 * COUT * 32 * 2;   // A LDS bytes per chunk-part
  __shared__ __align__(16) char lds[ABYTES + 10240];  // + B: 160 rows x 32 bf16
  u16* As = (u16*)lds;                 // [tap][co][ci32]
  u16* Bs = (u16*)(lds + ABYTES);      // [(ll_in*16+t)][ci32]
  uint32_t* Bw = (uint32_t*)Bs;

  int b = blockIdx.x, lb = blockIdx.y * 8;
  int tid = threadIdx.x;
  int lane = tid & 63, wid = tid >> 6;
  int wx = wid & 1, wy = wid >> 1;
  int q = lane >> 4, xx = lane & 15;

  f32x4 acc[MT][4];
#pragma unroll
  for (int mt = 0; mt < MT; ++mt)
#pragma unroll
    for (int nt = 0; nt < 4; ++nt) acc[mt][nt] = (f32x4){0.f, 0.f, 0.f, 0.f};

  for (int chunk = 0; chunk < NCHUNK; ++chunk) {
    int c0 = chunk * 32;
    bf16x8 Bf[6];
    for (int part = 0; part < 3; ++part) {
      // stage A (current part, current ci-chunk): rows of 32 bf16 = 4x16B
      const u16* Agp = Ag + part * (3 * COUT * CIN);
      for (int s = tid; s < 3 * COUT * 4; s += 256) {
        int r = s >> 2, o = s & 3;
        uint4 v = *(const uint4*)(Agp + r * CIN + c0 + o * 8);
        *(uint4*)(As + r * 32 + o * 8) = v;
      }
      // stage B once per chunk (spike bits -> bf16 0/1)
      if (part == 0 && tid < 160) {
        int cp = tid & 15, row = tid >> 4;   // ci pair, l row (lg = lb+row-1)
        int lg = lb + row - 1;
        uint32_t v0 = 0, v1 = 0;
        if (lg >= 0 && lg < 128) {
          const u16* p = sbits_in + ((size_t)b * CIN + c0 + 2 * cp) * 128 + lg;
          v0 = p[0]; v1 = p[128];
        }
#pragma unroll
        for (int t = 0; t < 16; ++t) {
          uint32_t wv = (((v0 >> t) & 1u) * 0x3F80u) |
                        ((((v1 >> t) & 1u) * 0x3F80u) << 16);
          Bw[(row * 16 + t) * 16 + cp] = wv;
        }
      }
      __syncthreads();
      if (part == 0) {
#pragma unroll
        for (int u = 0; u < 6; ++u)
          Bf[u] = *(const bf16x8*)(Bs + ((wx * 4 + u) * 16 + xx) * 32 + q * 8);
      }
#pragma unroll
      for (int tap = 0; tap < 3; ++tap)
#pragma unroll
        for (int mt = 0; mt < MT; ++mt) {
          bf16x8 Af = *(const bf16x8*)(As + (tap * COUT + wy * WM + mt * 16 + xx) * 32 + q * 8);
#pragma unroll
          for (int nt = 0; nt < 4; ++nt)
            acc[mt][nt] = __builtin_amdgcn_mfma_f32_16x16x32_bf16(
                Af, Bf[nt + tap], acc[mt][nt], 0, 0, 0);
        }
      __syncthreads();
    }
  }

  // epilogue: transpose C tiles through per-wave LDS scratch (pad 18), LIF, pack
  float* scr = (float*)lds + wid * (4 * 16 * 18);   // 4608 B per wave
#pragma unroll
  for (int mt = 0; mt < MT; ++mt) {
#pragma unroll
    for (int nt = 0; nt < 4; ++nt)
#pragma unroll
      for (int r = 0; r < 4; ++r)
        scr[(nt * 16 + q * 4 + r) * 18 + xx] = acc[mt][nt][r];
    __syncthreads();
    // lane -> (tile q = ll offset, co_in = xx); read t-serial row
    int co = wy * WM + mt * 16 + xx;
    int l = lb + wx * 4 + q;
    float bc = bias[co];
    const float* rowp = scr + (q * 16 + xx) * 18;
    float mm = 0.f, sp = 0.f;
    uint32_t bits = 0;
#pragma unroll
    for (int t = 0; t < 16; ++t) {
      float cur = rowp[t] + bc;
      mm = BETA * mm + cur - sp;
      bool s = mm > 1.0f;
      bits |= ((uint32_t)s) << t;
      sp = s ? 1.0f : 0.0f;
    }
    sbits_out[((size_t)b * COUT + co) * 128 + l] = (u16)bits;
    __syncthreads();
  }
}

// ---------------------------------------------------------------------------
// head: conv4 (64->2) + LIF4, fc1 (256->100) + LIF5, fc2 accumulated (popcount)
// ---------------------------------------------------------------------------
__global__ __launch_bounds__(256) void head_kernel(
    const u16* __restrict__ s3bits, const float* __restrict__ W4,
    const float* __restrict__ b4, const float* __restrict__ fw1T,
    const float* __restrict__ fb1, const float* __restrict__ fw2T,
    const float* __restrict__ fb2, float* __restrict__ out) {
  __shared__ u16 s3l[64][130];
  __shared__ float W4l[384];
  __shared__ u16 flat4[256];
  __shared__ u16 s5b[100];
  int b = blockIdx.x, tid = threadIdx.x;

  for (int i = tid; i < 64 * 130; i += 256) {
    int ci = i / 130, idx = i % 130, lg = idx - 1;
    s3l[ci][idx] = (lg >= 0 && lg < 128) ? s3bits[((size_t)b * 64 + ci) * 128 + lg] : (u16)0;
  }
  for (int i = tid; i < 384; i += 256) W4l[i] = W4[i];
  __syncthreads();

  {
    int co = tid >> 7, l = tid & 127;
    float acc4[16];
#pragma unroll
    for (int t = 0; t < 16; ++t) acc4[t] = 0.f;
    for (int ci = 0; ci < 64; ++ci) {
#pragma unroll
      for (int k = 0; k < 3; ++k) {
        float wv = W4l[(co * 64 + ci) * 3 + k];
        uint32_t msk = s3l[ci][l + k];
#pragma unroll
        for (int t = 0; t < 16; ++t)
          acc4[t] = fmaf(wv, (float)((msk >> t) & 1u), acc4[t]);
      }
    }
    float bc = b4[co];
    float m = 0.f, sp = 0.f;
    uint32_t bits = 0;
#pragma unroll
    for (int t = 0; t < 16; ++t) {
      m = BETA * m + (acc4[t] + bc) - sp;
      bool s = m > 1.0f;
      bits |= ((uint32_t)s) << t;
      sp = s ? 1.0f : 0.0f;
    }
    flat4[tid] = (u16)bits;
  }
  __syncthreads();

  if (tid < 100) {
    float acc5[16];
#pragma unroll
    for (int t = 0; t < 16; ++t) acc5[t] = 0.f;
    for (int f = 0; f < 256; ++f) {
      float wv = fw1T[f * 100 + tid];
      uint32_t msk = flat4[f];
#pragma unroll
      for (int t = 0; t < 16; ++t)
        acc5[t] = fmaf(wv, (float)((msk >> t) & 1u), acc5[t]);
    }
    float bc = fb1[tid];
    float m = 0.f, sp = 0.f;
    uint32_t bits = 0;
#pragma unroll
    for (int t = 0; t < 16; ++t) {
      m = BETA * m + (acc5[t] + bc) - sp;
      bool s = m > 1.0f;
      bits |= ((uint32_t)s) << t;
      sp = s ? 1.0f : 0.0f;
    }
    s5b[tid] = (u16)bits;
  }
  __syncthreads();

  if (tid < 40) {
    float a = 0.f;
    for (int i = 0; i < 100; ++i) {
      float wv = fw2T[i * 40 + tid];
      a = fmaf(wv, (float)__popc((uint32_t)s5b[i]), a);
    }
    out[b * 40 + tid] = a * 0.0625f + fb2[tid];
  }
}

// ---------------------------------------------------------------------------
extern "C" void kernel_launch(void* const* d_in, const int* in_sizes, int n_in,
                              void* d_out, int out_size, void* d_ws, size_t ws_size,
                              hipStream_t stream) {
  const float* x   = (const float*)d_in[0];
  const float* W1  = (const float*)d_in[1];
  const float* b1  = (const float*)d_in[2];
  const float* W2  = (const float*)d_in[3];
  const float* b2  = (const float*)d_in[4];
  const float* W3  = (const float*)d_in[5];
  const float* b3  = (const float*)d_in[6];
  const float* W4  = (const float*)d_in[7];
  const float* b4  = (const float*)d_in[8];
  const float* fw1 = (const float*)d_in[9];
  const float* fb1 = (const float*)d_in[10];
  const float* fw2 = (const float*)d_in[11];
  const float* fb2 = (const float*)d_in[12];
  float* out = (float*)d_out;

  char* ws = (char*)d_ws;
  u16*   A2   = (u16*)(ws);                     // 589824 B  [part][tap][co][ci]
  u16*   A3   = (u16*)(ws + 589824);            // 147456 B
  float* fw1T = (float*)(ws + 737280);          // 102400 B
  float* fw2T = (float*)(ws + 839680);          //  16000 B (pad to 856064)
  u16*   s1b  = (u16*)(ws + 856064);            // 134217728 B
  u16*   s2b  = (u16*)(ws + 856064 + 134217728);//  67108864 B
  u16*   s3b  = s1b;                            // alias: s1 dead after conv2
  // total: 202,182,656 B

  prep_kernel<<<dim3(596), dim3(256), 0, stream>>>(W2, W3, fw1, fw2, A2, A3, fw1T, fw2T);
  conv1_lif_kernel<<<dim3(2048, 32), dim3(256), 0, stream>>>(x, W1, b1, s1b);
  conv_mfma_kernel<256, 128><<<dim3(2048, 16), dim3(256), 0, stream>>>(s1b, A2, b2, s2b);
  conv_mfma_kernel<128, 64><<<dim3(2048, 16), dim3(256), 0, stream>>>(s2b, A3, b3, s3b);
  head_kernel<<<dim3(2048), dim3(256), 0, stream>>>(s3b, W4, b4, fw1T, fb1, fw2T, fb2, out);
}

// Round 3
// 2425.442 us; speedup vs baseline: 8.2972x; 1.3381x over previous
//
#include <hip/hip_runtime.h>
#include <stdint.h>

#define BETA 0.9f

typedef unsigned short u16;
typedef _Float16 f16x8 __attribute__((ext_vector_type(8)));
typedef float f32x4 __attribute__((ext_vector_type(4)));

// async global->LDS, 16B per lane; lds ptr must be wave-uniform base.
__device__ __forceinline__ void async_copy16(const void* g, void* l) {
  __builtin_amdgcn_global_load_lds(
      (const __attribute__((address_space(1))) uint32_t*)g,
      (__attribute__((address_space(3))) uint32_t*)l, 16, 0, 0);
}

// ---------------------------------------------------------------------------
// prep: fp16 2-split of W2/W3 (w = hi + mid*2^-11, |err| <= 7.5e-9/weight),
// chunked layout A[chunk][part][tap][co][ci32] so each (chunk,part) block is
// one contiguous 24KB (conv2) / 12KB (conv3) copy for global_load_lds.
// Also transpose fc weights.
// ---------------------------------------------------------------------------
__global__ void prep_kernel(const float* __restrict__ W2, const float* __restrict__ W3,
                            const float* __restrict__ fw1, const float* __restrict__ fw2,
                            u16* __restrict__ A2c, u16* __restrict__ A3c,
                            float* __restrict__ fw1T, float* __restrict__ fw2T) {
  int o = blockIdx.x * 256 + threadIdx.x;
  if (o < 98304) {  // W2: (tap, co, ci), 3*128*256
    int tap = o >> 15, r = o & 32767, co = r >> 8, ci = r & 255;
    float w = W2[(co * 256 + ci) * 3 + tap];
    _Float16 h = (_Float16)w;
    float r1 = w - (float)h;
    _Float16 m = (_Float16)(r1 * 2048.0f);
    u16 hb, mb;
    __builtin_memcpy(&hb, &h, 2);
    __builtin_memcpy(&mb, &m, 2);
    int chunk = ci >> 5, cl = ci & 31;
    A2c[(((chunk * 2 + 0) * 3 + tap) * 128 + co) * 32 + cl] = hb;
    A2c[(((chunk * 2 + 1) * 3 + tap) * 128 + co) * 32 + cl] = mb;
  }
  int o2 = o - 98304;  // W3: (tap, co, ci), 3*64*128
  if (o2 >= 0 && o2 < 24576) {
    int tap = o2 >> 13, r = o2 & 8191, co = r >> 7, ci = r & 127;
    float w = W3[(co * 128 + ci) * 3 + tap];
    _Float16 h = (_Float16)w;
    float r1 = w - (float)h;
    _Float16 m = (_Float16)(r1 * 2048.0f);
    u16 hb, mb;
    __builtin_memcpy(&hb, &h, 2);
    __builtin_memcpy(&mb, &m, 2);
    int chunk = ci >> 5, cl = ci & 31;
    A3c[(((chunk * 2 + 0) * 3 + tap) * 64 + co) * 32 + cl] = hb;
    A3c[(((chunk * 2 + 1) * 3 + tap) * 64 + co) * 32 + cl] = mb;
  }
  int o3 = o - (98304 + 24576);
  if (o3 >= 0 && o3 < 25600) {
    int f = o3 / 100, i = o3 % 100;
    fw1T[o3] = fw1[i * 256 + f];
  }
  int o4 = o - (98304 + 24576 + 25600);
  if (o4 >= 0 && o4 < 4000) {
    int i = o4 / 40, j = o4 % 40;
    fw2T[o4] = fw2[j * 100 + i];
  }
}

// ---------------------------------------------------------------------------
// conv1 (2->256, K=5, pad=2) + LIF1; cur constant across t.
// ---------------------------------------------------------------------------
__global__ __launch_bounds__(256) void conv1_lif_kernel(
    const float* __restrict__ x, const float* __restrict__ W1,
    const float* __restrict__ b1, u16* __restrict__ s1bits) {
  __shared__ float xl[2][132];
  int b = blockIdx.x;
  int tid = threadIdx.x;
  for (int i = tid; i < 264; i += 256) {
    int ci = i / 132, idx = i % 132, lg = idx - 2;
    xl[ci][idx] = (lg >= 0 && lg < 128) ? x[(b * 2 + ci) * 128 + lg] : 0.0f;
  }
  __syncthreads();
  int co = blockIdx.y * 8 + (tid >> 5);
  int tx = tid & 31;
  float w[2][5];
#pragma unroll
  for (int ci = 0; ci < 2; ++ci)
#pragma unroll
    for (int k = 0; k < 5; ++k) w[ci][k] = W1[(co * 2 + ci) * 5 + k];
  float bias = b1[co];
  float cur[4];
#pragma unroll
  for (int j = 0; j < 4; ++j) {
    float acc = bias;
#pragma unroll
    for (int ci = 0; ci < 2; ++ci)
#pragma unroll
      for (int k = 0; k < 5; ++k) acc += w[ci][k] * xl[ci][4 * tx + j + k];
    cur[j] = acc;
  }
  float m[4] = {0.f, 0.f, 0.f, 0.f}, sp[4] = {0.f, 0.f, 0.f, 0.f};
  uint32_t bits[4] = {0u, 0u, 0u, 0u};
#pragma unroll
  for (int t = 0; t < 16; ++t) {
#pragma unroll
    for (int j = 0; j < 4; ++j) {
      m[j] = BETA * m[j] + cur[j] - sp[j];
      bool s = m[j] > 1.0f;
      bits[j] |= ((uint32_t)s) << t;
      sp[j] = s ? 1.0f : 0.0f;
    }
  }
  uint2 v;
  v.x = (bits[0] & 0xFFFFu) | (bits[1] << 16);
  v.y = (bits[2] & 0xFFFFu) | (bits[3] << 16);
  *(uint2*)&s1bits[(b * 256 + co) * 128 + 4 * tx] = v;
}

// ---------------------------------------------------------------------------
// MFMA conv (CIN->COUT, K=3, pad=1) + LIF on bit-packed spikes.
// fp16 2-split weights (hi + mid*2^-11): 2 MFMA passes, 2 acc sets.
// A staged per (chunk,part) via global_load_lds (contiguous 24KB/12KB copy);
// B (spikes->f16 0/1) staged once per chunk.
// ---------------------------------------------------------------------------
template <int CIN, int COUT>
__global__ __launch_bounds__(256, 3) void conv_mfma_kernel(
    const u16* __restrict__ sbits_in, const u16* __restrict__ Agc,
    const float* __restrict__ bias, u16* __restrict__ sbits_out) {
  constexpr int WM = COUT / 2;        // wave M extent
  constexpr int MT = COUT / 32;       // m-tiles per wave
  constexpr int NCHUNK = CIN / 32;
  constexpr int ABYTES = 3 * COUT * 32 * 2;  // per (chunk,part) A block
  constexpr int AW = ABYTES / 4;             // per-wave segment
  constexpr int AISS = AW / 1024;            // 1KB issues per wave
  __shared__ __align__(16) char lds[ABYTES + 10240];  // + B: 160 rows x 32 f16
  u16* As = (u16*)lds;                 // [tap][co][ci32]
  u16* Bs = (u16*)(lds + ABYTES);      // [(l_row*16+t)][ci32]
  uint32_t* Bw = (uint32_t*)Bs;

  int b = blockIdx.x, lb = blockIdx.y * 8;
  int tid = threadIdx.x;
  int lane = tid & 63, wid = tid >> 6;
  int wx = wid & 1, wy = wid >> 1;
  int q = lane >> 4, xx = lane & 15;

  f32x4 acc[2][MT][4];
#pragma unroll
  for (int p = 0; p < 2; ++p)
#pragma unroll
    for (int mt = 0; mt < MT; ++mt)
#pragma unroll
      for (int nt = 0; nt < 4; ++nt) acc[p][mt][nt] = (f32x4){0.f, 0.f, 0.f, 0.f};

  for (int chunk = 0; chunk < NCHUNK; ++chunk) {
    int c0 = chunk * 32;
    f16x8 Bf[6];
#pragma unroll
    for (int part = 0; part < 2; ++part) {
      // async stage A: contiguous (chunk,part) block, wave-sliced
      const char* gsrc = (const char*)Agc + (size_t)(chunk * 2 + part) * ABYTES + wid * AW + lane * 16;
      char* ldst = (char*)As + wid * AW;
#pragma unroll
      for (int i = 0; i < AISS; ++i)
        async_copy16(gsrc + i * 1024, ldst + i * 1024);
      // stage B once per chunk (spike bits -> f16 0/1)
      if (part == 0 && tid < 160) {
        int cp = tid & 15, row = tid >> 4;  // ci pair, l row (lg = lb+row-1)
        int lg = lb + row - 1;
        uint32_t v0 = 0, v1 = 0;
        if (lg >= 0 && lg < 128) {
          const u16* p = sbits_in + ((size_t)b * CIN + c0 + 2 * cp) * 128 + lg;
          v0 = p[0]; v1 = p[128];
        }
#pragma unroll
        for (int t = 0; t < 16; ++t) {
          uint32_t wv = (((v0 >> t) & 1u) * 0x3C00u) |
                        ((((v1 >> t) & 1u) * 0x3C00u) << 16);
          Bw[(row * 16 + t) * 16 + cp] = wv;
        }
      }
      __syncthreads();
      if (part == 0) {
#pragma unroll
        for (int u = 0; u < 6; ++u)
          Bf[u] = *(const f16x8*)(Bs + ((wx * 4 + u) * 16 + xx) * 32 + q * 8);
      }
#pragma unroll
      for (int tap = 0; tap < 3; ++tap)
#pragma unroll
        for (int mt = 0; mt < MT; ++mt) {
          f16x8 Af = *(const f16x8*)(As + (tap * COUT + wy * WM + mt * 16 + xx) * 32 + q * 8);
#pragma unroll
          for (int nt = 0; nt < 4; ++nt)
            acc[part][mt][nt] = __builtin_amdgcn_mfma_f32_16x16x32_f16(
                Af, Bf[nt + tap], acc[part][mt][nt], 0, 0, 0);
        }
      __syncthreads();
    }
  }

  // epilogue: combine split parts, transpose via per-wave LDS scratch, LIF, pack
  float* scr = (float*)lds + wid * (4 * 16 * 18);
#pragma unroll
  for (int mt = 0; mt < MT; ++mt) {
#pragma unroll
    for (int nt = 0; nt < 4; ++nt)
#pragma unroll
      for (int r = 0; r < 4; ++r)
        scr[(nt * 16 + q * 4 + r) * 18 + xx] =
            acc[0][mt][nt][r] + acc[1][mt][nt][r] * (1.0f / 2048.0f);
    __syncthreads();
    int co = wy * WM + mt * 16 + xx;
    int l = lb + wx * 4 + q;
    float bc = bias[co];
    const float* rowp = scr + (q * 16 + xx) * 18;
    float mm = 0.f, sp = 0.f;
    uint32_t bits = 0;
#pragma unroll
    for (int t = 0; t < 16; ++t) {
      float cur = rowp[t] + bc;
      mm = BETA * mm + cur - sp;
      bool s = mm > 1.0f;
      bits |= ((uint32_t)s) << t;
      sp = s ? 1.0f : 0.0f;
    }
    sbits_out[((size_t)b * COUT + co) * 128 + l] = (u16)bits;
    __syncthreads();
  }
}

// ---------------------------------------------------------------------------
// head: conv4 (64->2) + LIF4, fc1 (256->100) + LIF5, fc2 accumulated (popcount)
// ---------------------------------------------------------------------------
__global__ __launch_bounds__(256) void head_kernel(
    const u16* __restrict__ s3bits, const float* __restrict__ W4,
    const float* __restrict__ b4, const float* __restrict__ fw1T,
    const float* __restrict__ fb1, const float* __restrict__ fw2T,
    const float* __restrict__ fb2, float* __restrict__ out) {
  __shared__ u16 s3l[64][130];
  __shared__ float W4l[384];
  __shared__ u16 flat4[256];
  __shared__ u16 s5b[100];
  int b = blockIdx.x, tid = threadIdx.x;

  for (int i = tid; i < 64 * 130; i += 256) {
    int ci = i / 130, idx = i % 130, lg = idx - 1;
    s3l[ci][idx] = (lg >= 0 && lg < 128) ? s3bits[((size_t)b * 64 + ci) * 128 + lg] : (u16)0;
  }
  for (int i = tid; i < 384; i += 256) W4l[i] = W4[i];
  __syncthreads();

  {
    int co = tid >> 7, l = tid & 127;
    float acc4[16];
#pragma unroll
    for (int t = 0; t < 16; ++t) acc4[t] = 0.f;
    for (int ci = 0; ci < 64; ++ci) {
#pragma unroll
      for (int k = 0; k < 3; ++k) {
        float wv = W4l[(co * 64 + ci) * 3 + k];
        uint32_t msk = s3l[ci][l + k];
#pragma unroll
        for (int t = 0; t < 16; ++t)
          acc4[t] = fmaf(wv, (float)((msk >> t) & 1u), acc4[t]);
      }
    }
    float bc = b4[co];
    float m = 0.f, sp = 0.f;
    uint32_t bits = 0;
#pragma unroll
    for (int t = 0; t < 16; ++t) {
      m = BETA * m + (acc4[t] + bc) - sp;
      bool s = m > 1.0f;
      bits |= ((uint32_t)s) << t;
      sp = s ? 1.0f : 0.0f;
    }
    flat4[tid] = (u16)bits;
  }
  __syncthreads();

  if (tid < 100) {
    float acc5[16];
#pragma unroll
    for (int t = 0; t < 16; ++t) acc5[t] = 0.f;
    for (int f = 0; f < 256; ++f) {
      float wv = fw1T[f * 100 + tid];
      uint32_t msk = flat4[f];
#pragma unroll
      for (int t = 0; t < 16; ++t)
        acc5[t] = fmaf(wv, (float)((msk >> t) & 1u), acc5[t]);
    }
    float bc = fb1[tid];
    float m = 0.f, sp = 0.f;
    uint32_t bits = 0;
#pragma unroll
    for (int t = 0; t < 16; ++t) {
      m = BETA * m + (acc5[t] + bc) - sp;
      bool s = m > 1.0f;
      bits |= ((uint32_t)s) << t;
      sp = s ? 1.0f : 0.0f;
    }
    s5b[tid] = (u16)bits;
  }
  __syncthreads();

  if (tid < 40) {
    float a = 0.f;
    for (int i = 0; i < 100; ++i) {
      float wv = fw2T[i * 40 + tid];
      a = fmaf(wv, (float)__popc((uint32_t)s5b[i]), a);
    }
    out[b * 40 + tid] = a * 0.0625f + fb2[tid];
  }
}

// ---------------------------------------------------------------------------
extern "C" void kernel_launch(void* const* d_in, const int* in_sizes, int n_in,
                              void* d_out, int out_size, void* d_ws, size_t ws_size,
                              hipStream_t stream) {
  const float* x   = (const float*)d_in[0];
  const float* W1  = (const float*)d_in[1];
  const float* b1  = (const float*)d_in[2];
  const float* W2  = (const float*)d_in[3];
  const float* b2  = (const float*)d_in[4];
  const float* W3  = (const float*)d_in[5];
  const float* b3  = (const float*)d_in[6];
  const float* W4  = (const float*)d_in[7];
  const float* b4  = (const float*)d_in[8];
  const float* fw1 = (const float*)d_in[9];
  const float* fb1 = (const float*)d_in[10];
  const float* fw2 = (const float*)d_in[11];
  const float* fb2 = (const float*)d_in[12];
  float* out = (float*)d_out;

  char* ws = (char*)d_ws;
  u16*   A2c  = (u16*)(ws);                     // 393216 B  [chunk][part][tap][co][ci]
  u16*   A3c  = (u16*)(ws + 393216);            //  98304 B
  float* fw1T = (float*)(ws + 491520);          // 102400 B
  float* fw2T = (float*)(ws + 593920);          //  16000 B (pad to 610304)
  u16*   s1b  = (u16*)(ws + 610304);            // 134217728 B
  u16*   s2b  = (u16*)(ws + 610304 + 134217728);//  67108864 B
  u16*   s3b  = s1b;                            // alias: s1 dead after conv2
  // total: 201,936,896 B

  prep_kernel<<<dim3(596), dim3(256), 0, stream>>>(W2, W3, fw1, fw2, A2c, A3c, fw1T, fw2T);
  conv1_lif_kernel<<<dim3(2048, 32), dim3(256), 0, stream>>>(x, W1, b1, s1b);
  conv_mfma_kernel<256, 128><<<dim3(2048, 16), dim3(256), 0, stream>>>(s1b, A2c, b2, s2b);
  conv_mfma_kernel<128, 64><<<dim3(2048, 16), dim3(256), 0, stream>>>(s2b, A3c, b3, s3b);
  head_kernel<<<dim3(2048), dim3(256), 0, stream>>>(s3b, W4, b4, fw1T, fb1, fw2T, fb2, out);
}